// Round 2
// baseline (954.869 us; speedup 1.0000x reference)
//
#include <hip/hip_runtime.h>
#include <math.h>

constexpr int NB = 32;    // batch
constexpr int NM = 20;    // modes
constexpr int NP = 8;     // points per mode (== EGO_FUT_TS)
constexpr int ND = 256;   // model dim
constexpr int NA = 32;    // agents
constexpr int NFF = 1024; // ffn dim
constexpr int NH = 128, NW = 128;
constexpr int HW = NH * NW;

// ---------------------------------------------------------------------------
// block-wide sum over 256 threads (4 waves)
__device__ __forceinline__ float blk_sum(float v, float* s_red) {
    for (int off = 32; off > 0; off >>= 1) v += __shfl_down(v, off, 64);
    int tid = threadIdx.x;
    __syncthreads();                    // protect s_red from previous call's readers
    if ((tid & 63) == 0) s_red[tid >> 6] = v;
    __syncthreads();
    return s_red[0] + s_red[1] + s_red[2] + s_red[3];
}

__device__ __forceinline__ float blk_ln(float x, const float* g, const float* bb, float* s_red) {
    int tid = threadIdx.x;
    float mean = blk_sum(x, s_red) * (1.0f / 256.0f);
    float xm = x - mean;
    float var = blk_sum(xm * xm, s_red) * (1.0f / 256.0f);
    return xm / sqrtf(var + 1e-5f) * g[tid] + bb[tid];
}

// ---------------------------------------------------------------------------
// Kernel 1: point-softmax + bilinear gather.
// gw[b,m,c]   = sum_p ptw[b,m,p] * sum_corner w*valid * bev[b,c,y,x]
// wsum[b,m]   = sum_p ptw * sum_corner w*valid   (scales the value bias)
__global__ void gather_kernel(const float* __restrict__ traj, const float* __restrict__ noisy,
                              const float* __restrict__ bev, const float* __restrict__ attn_w,
                              const float* __restrict__ attn_b,
                              float* __restrict__ gw, float* __restrict__ wsumw) {
    int blk = blockIdx.x;
    int b = blk / NM, tid = threadIdx.x;
    __shared__ float s_traj[ND];
    __shared__ float s_ptw[NP];
    __shared__ float s_w[32];
    __shared__ int s_idx[32];

    s_traj[tid] = traj[(size_t)blk * ND + tid];
    __syncthreads();
    if (tid < NP) {
        float acc = attn_b[tid];
        for (int c = 0; c < ND; c++) acc += s_traj[c] * attn_w[c * NP + tid];
        s_ptw[tid] = acc;
    }
    __syncthreads();
    if (tid == 0) {
        float mx = s_ptw[0];
        for (int p = 1; p < NP; p++) mx = fmaxf(mx, s_ptw[p]);
        float e[NP], sum = 0.f;
        for (int p = 0; p < NP; p++) { e[p] = expf(s_ptw[p] - mx); sum += e[p]; }
        for (int p = 0; p < NP; p++) s_ptw[p] = e[p] / sum;
    }
    __syncthreads();
    if (tid < 32) {
        int p = tid >> 2, corner = tid & 3;
        float gx = noisy[((size_t)blk * NP + p) * 2 + 0] * (1.0f / 32.0f);
        float gy = noisy[((size_t)blk * NP + p) * 2 + 1] * (1.0f / 32.0f);
        float x = (gx + 1.0f) * (NW * 0.5f) - 0.5f;
        float y = (gy + 1.0f) * (NH * 0.5f) - 0.5f;
        float x0 = floorf(x), y0 = floorf(y);
        int dx = corner & 1, dy = corner >> 1;
        float wx = dx ? (x - x0) : (x0 + 1.0f - x);
        float wy = dy ? (y - y0) : (y0 + 1.0f - y);
        float xi = x0 + (float)dx, yi = y0 + (float)dy;
        bool valid = (xi >= 0.f) && (xi <= (float)(NW - 1)) && (yi >= 0.f) && (yi <= (float)(NH - 1));
        int xc = (int)fminf(fmaxf(xi, 0.f), (float)(NW - 1));
        int yc = (int)fminf(fmaxf(yi, 0.f), (float)(NH - 1));
        s_w[tid] = wx * wy * (valid ? 1.f : 0.f) * s_ptw[p];
        s_idx[tid] = yc * NW + xc;
    }
    __syncthreads();
    if (tid == 0) {
        float s = 0.f;
        for (int j = 0; j < 32; j++) s += s_w[j];
        wsumw[blk] = s;
    }
    const float* base = bev + (size_t)b * ND * HW + (size_t)tid * HW;
    float acc = 0.f;
    for (int j = 0; j < 32; j++) acc += s_w[j] * base[s_idx[j]];
    gw[(size_t)blk * ND + tid] = acc;
}

// ---------------------------------------------------------------------------
// Kernel 2: agents K/V projections. one block per (b, a)
__global__ void kv_kernel(const float* __restrict__ agents,
                          const float* __restrict__ wk, const float* __restrict__ bk,
                          const float* __restrict__ wv, const float* __restrict__ bv,
                          float* __restrict__ K1, float* __restrict__ V1) {
    int blk = blockIdx.x, tid = threadIdx.x;
    __shared__ float s_row[ND];
    s_row[tid] = agents[(size_t)blk * ND + tid];
    __syncthreads();
    float ak = bk[tid], av = bv[tid];
    for (int c = 0; c < ND; c++) {
        float r = s_row[c];
        ak += r * wk[c * ND + tid];
        av += r * wv[c * ND + tid];
    }
    K1[(size_t)blk * ND + tid] = ak;
    V1[(size_t)blk * ND + tid] = av;
}

// ---------------------------------------------------------------------------
// Kernel 3: per-batch precompute. Ego attention has Lk=1 => softmax == 1, so
// the whole ego-MHA collapses to u[b] = (ego@wv+bv)@wo+bo (q/k weights dead).
// Also: ss[b] = mish(time_embed[b]) @ mod_w + mod_b.
__global__ void perb_kernel(const float* __restrict__ ego,
                            const float* __restrict__ eq_wv, const float* __restrict__ eq_bv,
                            const float* __restrict__ eq_wo, const float* __restrict__ eq_bo,
                            const float* __restrict__ time_embed,
                            const float* __restrict__ mod_w, const float* __restrict__ mod_b,
                            float* __restrict__ u, float* __restrict__ ss) {
    int b = blockIdx.x, tid = threadIdx.x;
    __shared__ float s_a[ND], s_b[ND];
    s_a[tid] = ego[(size_t)b * ND + tid];
    __syncthreads();
    float v = eq_bv[tid];
    for (int c = 0; c < ND; c++) v += s_a[c] * eq_wv[c * ND + tid];
    s_b[tid] = v;
    __syncthreads();
    float o = eq_bo[tid];
    for (int c = 0; c < ND; c++) o += s_b[c] * eq_wo[c * ND + tid];
    u[(size_t)b * ND + tid] = o;

    float te = time_embed[(size_t)b * ND + tid];
    float sp = log1pf(expf(te));          // softplus
    float me = te * tanhf(sp);            // mish
    __syncthreads();                      // all reads of s_a done
    s_a[tid] = me;
    __syncthreads();
    for (int jj = 0; jj < 2; jj++) {
        int j = tid + jj * ND;
        float acc = mod_b[j];
        for (int c = 0; c < ND; c++) acc += s_a[c] * mod_w[(size_t)c * 2 * ND + j];
        ss[(size_t)b * 2 * ND + j] = acc;
    }
}

// ---------------------------------------------------------------------------
// Kernel 4: per-token megakernel. one block per (b, m), 256 threads.
struct MegaW {
    const float *traj, *noisy;
    const float *bvw, *bvb, *bow, *bob;
    const float *wq, *bq, *wo, *bo;
    const float *n1g, *n1b, *n2g, *n2b;
    const float *fw1, *fb1, *fw2, *fb2, *n3g, *n3b;
    const float *cw1, *cb1, *cl1g, *cl1b, *cw2, *cb2, *cl2g, *cl2b, *cw3, *cb3;
    const float *rw1, *rb1, *rw2, *rb2, *rw3, *rb3;
};

__global__ void mega_kernel(const float* __restrict__ gw, const float* __restrict__ wsumw,
                            const float* __restrict__ K1, const float* __restrict__ V1,
                            const float* __restrict__ u, const float* __restrict__ ss,
                            MegaW W, float* __restrict__ out) {
    int blk = blockIdx.x;
    int b = blk / NM, tid = threadIdx.x;
    __shared__ float s_a[ND], s_b[ND], s_h[NFF], s_sc[ND], s_red[4];

    // --- bev value GEMM: sampled' = gw @ W_v + b_v * wsum
    s_sc[tid] = gw[(size_t)blk * ND + tid];
    float wsw = wsumw[blk];
    __syncthreads();
    float acc = W.bvb[tid] * wsw;
    for (int c = 0; c < ND; c++) acc += s_sc[c] * W.bvw[c * ND + tid];
    s_b[tid] = acc;
    __syncthreads();
    // --- bev out GEMM + residual with traj_feature -> t0 in s_a
    acc = W.bob[tid] + W.traj[(size_t)blk * ND + tid];
    for (int c = 0; c < ND; c++) acc += s_b[c] * W.bow[c * ND + tid];
    s_a[tid] = acc;
    __syncthreads();
    // --- agents attention: q projection
    acc = W.bq[tid];
    for (int c = 0; c < ND; c++) acc += s_a[c] * W.wq[c * ND + tid];
    s_b[tid] = acc;   // q
    __syncthreads();
    // scores: thread t -> head h = t>>5, key k = t&31
    int h = tid >> 5, kk = tid & 31;
    {
        const float* Krow = K1 + ((size_t)(b * NA + kk)) * ND + h * 32;
        float sc = 0.f;
        for (int j = 0; j < 32; j++) sc += s_b[h * 32 + j] * Krow[j];
        s_sc[tid] = sc * 0.17677669529663687f;   // 1/sqrt(32)
    }
    __syncthreads();
    // softmax over the 32 keys of this head
    {
        float mx = -1e30f;
        for (int j = 0; j < 32; j++) mx = fmaxf(mx, s_sc[h * 32 + j]);
        float den = 0.f;
        for (int j = 0; j < 32; j++) den += expf(s_sc[h * 32 + j] - mx);
        float p = expf(s_sc[tid] - mx) / den;
        __syncthreads();
        s_sc[tid] = p;
        __syncthreads();
    }
    // attn out: o[d], d = tid, head = tid>>5
    {
        const float* Vb = V1 + (size_t)b * NA * ND;
        float o = 0.f;
        for (int k = 0; k < 32; k++) o += s_sc[h * 32 + k] * Vb[(size_t)k * ND + tid];
        __syncthreads();
        s_b[tid] = o;
        __syncthreads();
    }
    // output proj + residual + LN1
    acc = W.bo[tid] + s_a[tid];
    for (int c = 0; c < ND; c++) acc += s_b[c] * W.wo[c * ND + tid];
    float t1 = blk_ln(acc, W.n1g, W.n1b, s_red);
    // ego (collapsed) residual + LN2
    float t2 = blk_ln(t1 + u[(size_t)b * ND + tid], W.n2g, W.n2b, s_red);
    __syncthreads();
    s_a[tid] = t2;
    __syncthreads();
    // --- FFN
    for (int jj = 0; jj < 4; jj++) {
        int i = tid + jj * ND;
        float a2 = W.fb1[i];
        for (int c = 0; c < ND; c++) a2 += s_a[c] * W.fw1[(size_t)c * NFF + i];
        s_h[i] = fmaxf(a2, 0.f);
    }
    __syncthreads();
    acc = W.fb2[tid];
    for (int i = 0; i < NFF; i++) acc += s_h[i] * W.fw2[(size_t)i * ND + tid];
    float t3 = blk_ln(acc, W.n3g, W.n3b, s_red);   // note: no residual, per reference
    // modulation
    float sc1 = ss[(size_t)b * 2 * ND + tid];
    float sh1 = ss[(size_t)b * 2 * ND + ND + tid];
    float tt = t3 * (1.f + sc1) + sh1;
    __syncthreads();
    s_a[tid] = tt;
    __syncthreads();
    // --- cls head
    acc = W.cb1[tid];
    for (int c = 0; c < ND; c++) acc += s_a[c] * W.cw1[c * ND + tid];
    float h1 = blk_ln(fmaxf(acc, 0.f), W.cl1g, W.cl1b, s_red);
    __syncthreads();
    s_b[tid] = h1;
    __syncthreads();
    acc = W.cb2[tid];
    for (int c = 0; c < ND; c++) acc += s_b[c] * W.cw2[c * ND + tid];
    float h2 = blk_ln(fmaxf(acc, 0.f), W.cl2g, W.cl2b, s_red);
    float pc = blk_sum(h2 * W.cw3[tid], s_red);
    if (tid == 0) out[(size_t)NB * NM * NP * 3 + blk] = pc + W.cb3[0];
    // --- reg head
    acc = W.rb1[tid];
    for (int c = 0; c < ND; c++) acc += s_a[c] * W.rw1[c * ND + tid];
    __syncthreads();
    s_b[tid] = fmaxf(acc, 0.f);
    __syncthreads();
    acc = W.rb2[tid];
    for (int c = 0; c < ND; c++) acc += s_b[c] * W.rw2[c * ND + tid];
    __syncthreads();
    s_b[tid] = fmaxf(acc, 0.f);
    __syncthreads();
    if (tid < 24) {
        float r3 = W.rb3[tid];
        for (int c = 0; c < ND; c++) r3 += s_b[c] * W.rw3[c * 24 + tid];
        int ts = tid / 3, k2 = tid % 3;
        float val;
        if (k2 < 2) val = r3 + W.noisy[((size_t)blk * NP + ts) * 2 + k2];
        else        val = tanhf(r3) * 3.14159265358979323846f;
        out[((size_t)blk * NP + ts) * 3 + k2] = val;
    }
}

// ---------------------------------------------------------------------------
extern "C" void kernel_launch(void* const* d_in, const int* in_sizes, int n_in,
                              void* d_out, int out_size, void* d_ws, size_t ws_size,
                              hipStream_t stream) {
    const float* traj   = (const float*)d_in[0];
    const float* noisy  = (const float*)d_in[1];
    const float* bev    = (const float*)d_in[2];
    const float* agents = (const float*)d_in[3];
    const float* ego    = (const float*)d_in[4];
    const float* temb   = (const float*)d_in[5];
    // d_in[6] = status_encoding (unused by reference forward path)
    const float* bvw = (const float*)d_in[7];
    const float* bvb = (const float*)d_in[8];
    const float* baw = (const float*)d_in[9];
    const float* bab = (const float*)d_in[10];
    const float* bow = (const float*)d_in[11];
    const float* bob = (const float*)d_in[12];
    const float* aq_wq = (const float*)d_in[13];
    const float* aq_bq = (const float*)d_in[14];
    const float* aq_wk = (const float*)d_in[15];
    const float* aq_bk = (const float*)d_in[16];
    const float* aq_wv = (const float*)d_in[17];
    const float* aq_bv = (const float*)d_in[18];
    const float* aq_wo = (const float*)d_in[19];
    const float* aq_bo = (const float*)d_in[20];
    // 21..24: eq_wq/bq/wk/bk are mathematically dead (Lk==1 softmax == 1)
    const float* eq_wv = (const float*)d_in[25];
    const float* eq_bv = (const float*)d_in[26];
    const float* eq_wo = (const float*)d_in[27];
    const float* eq_bo = (const float*)d_in[28];
    const float* fw1 = (const float*)d_in[29];
    const float* fb1 = (const float*)d_in[30];
    const float* fw2 = (const float*)d_in[31];
    const float* fb2 = (const float*)d_in[32];
    const float* n1g = (const float*)d_in[33];
    const float* n1b = (const float*)d_in[34];
    const float* n2g = (const float*)d_in[35];
    const float* n2b = (const float*)d_in[36];
    const float* n3g = (const float*)d_in[37];
    const float* n3b = (const float*)d_in[38];
    const float* modw = (const float*)d_in[39];
    const float* modb = (const float*)d_in[40];
    const float* cw1 = (const float*)d_in[41];
    const float* cb1 = (const float*)d_in[42];
    const float* cl1g = (const float*)d_in[43];
    const float* cl1b = (const float*)d_in[44];
    const float* cw2 = (const float*)d_in[45];
    const float* cb2 = (const float*)d_in[46];
    const float* cl2g = (const float*)d_in[47];
    const float* cl2b = (const float*)d_in[48];
    const float* cw3 = (const float*)d_in[49];
    const float* cb3 = (const float*)d_in[50];
    const float* rw1 = (const float*)d_in[51];
    const float* rb1 = (const float*)d_in[52];
    const float* rw2 = (const float*)d_in[53];
    const float* rb2 = (const float*)d_in[54];
    const float* rw3 = (const float*)d_in[55];
    const float* rb3 = (const float*)d_in[56];

    float* ws = (float*)d_ws;
    float* gw    = ws;                 // 640*256
    float* wsumw = ws + 163840;        // 640
    float* K1    = ws + 164480;        // 32*32*256
    float* V1    = ws + 426624;        // 32*32*256
    float* u     = ws + 688768;        // 32*256
    float* ssb   = ws + 696960;        // 32*512

    gather_kernel<<<dim3(NB * NM), dim3(256), 0, stream>>>(traj, noisy, bev, baw, bab, gw, wsumw);
    kv_kernel<<<dim3(NB * NA), dim3(256), 0, stream>>>(agents, aq_wk, aq_bk, aq_wv, aq_bv, K1, V1);
    perb_kernel<<<dim3(NB), dim3(256), 0, stream>>>(ego, eq_wv, eq_bv, eq_wo, eq_bo, temb, modw, modb, u, ssb);

    MegaW W;
    W.traj = traj; W.noisy = noisy;
    W.bvw = bvw; W.bvb = bvb; W.bow = bow; W.bob = bob;
    W.wq = aq_wq; W.bq = aq_bq; W.wo = aq_wo; W.bo = aq_bo;
    W.n1g = n1g; W.n1b = n1b; W.n2g = n2g; W.n2b = n2b;
    W.fw1 = fw1; W.fb1 = fb1; W.fw2 = fw2; W.fb2 = fb2; W.n3g = n3g; W.n3b = n3b;
    W.cw1 = cw1; W.cb1 = cb1; W.cl1g = cl1g; W.cl1b = cl1b;
    W.cw2 = cw2; W.cb2 = cb2; W.cl2g = cl2g; W.cl2b = cl2b; W.cw3 = cw3; W.cb3 = cb3;
    W.rw1 = rw1; W.rb1 = rb1; W.rw2 = rw2; W.rb2 = rb2; W.rw3 = rw3; W.rb3 = rb3;

    mega_kernel<<<dim3(NB * NM), dim3(256), 0, stream>>>(gw, wsumw, K1, V1, u, ssb, W, (float*)d_out);
}

// Round 3
// 897.336 us; speedup vs baseline: 1.0641x; 1.0641x over previous
//
#include <hip/hip_runtime.h>
#include <math.h>

constexpr int NB = 32;    // batch
constexpr int NM = 20;    // modes
constexpr int NP = 8;     // points per mode (== EGO_FUT_TS)
constexpr int ND = 256;   // model dim
constexpr int NA = 32;    // agents
constexpr int NFF = 1024; // ffn dim
constexpr int NH = 128, NW = 128;
constexpr int HW = NH * NW;

// packed bf16 weight region offsets (in bf16 elements) inside d_ws
constexpr int PK_BVW = 0;
constexpr int PK_BOW = 65536;
constexpr int PK_WQ  = 131072;
constexpr int PK_WO  = 196608;
constexpr int PK_CW1 = 262144;
constexpr int PK_CW2 = 327680;
constexpr int PK_RW1 = 393216;
constexpr int PK_RW2 = 458752;
constexpr int PK_WK  = 524288;
constexpr int PK_WV  = 589824;
constexpr int PK_FW1 = 655360;
constexpr int PK_FW2 = 917504;
constexpr int PK_TOTAL = 1179648;

// float-offsets in workspace
constexpr int WS_GW   = 0;              // 640*256
constexpr int WS_WSUM = 163840;         // 640
constexpr int WS_K1   = 164480;         // 1024*256
constexpr int WS_V1   = 426624;         // 1024*256
constexpr int WS_U    = 688768;         // 32*256
constexpr int WS_SS   = 696960;         // 32*512
constexpr int WS_PACK = 720896;         // bf16 area starts here (8B aligned)

// ---------------------------------------------------------------------------
// decode 2 bf16 (halfwords of u) to fp32
__device__ __forceinline__ void dec2(unsigned u, float& f0, float& f1) {
    union { unsigned x; float f; } a, b;
    a.x = u << 16;
    b.x = u & 0xffff0000u;
    f0 = a.f; f1 = b.f;
}

__device__ __forceinline__ float fma4(float4 a, uint2 w, float acc) {
    float w0, w1, w2, w3;
    dec2(w.x, w0, w1);
    dec2(w.y, w2, w3);
    acc += a.x * w0;
    acc += a.y * w1;
    acc += a.z * w2;
    acc += a.w * w3;
    return acc;
}

// GEMM col for K=256, N=256: acc += sum_c sa[c] * W[c][tid]
__device__ __forceinline__ float gemm256(const uint2* __restrict__ wp, const float* __restrict__ sa,
                                         int tid, float acc) {
    const float4* a4 = (const float4*)sa;
    #pragma unroll 8
    for (int c4 = 0; c4 < 64; ++c4) {
        float4 a = a4[c4];
        uint2 w = wp[(c4 << 8) + tid];
        acc = fma4(a, w, acc);
    }
    return acc;
}

// ---------------------------------------------------------------------------
// Kernel 0: pack fp32 weights -> bf16 [K/4][N][4] layout.
struct PackArgs {
    const float* src[12];
    int log2N[12];
    int elems[12];
    int dstoff[12];
};

__global__ void pack_kernel(PackArgs pa, unsigned short* __restrict__ dst) {
    int e = blockIdx.x * 256 + threadIdx.x;
    int seg = 0;
    while (seg < 12 && e >= pa.elems[seg]) { e -= pa.elems[seg]; seg++; }
    if (seg >= 12) return;
    int lg = pa.log2N[seg];
    int N = 1 << lg;
    int c = e >> lg;
    int n = e & (N - 1);
    float v = pa.src[seg][e];
    // bf16 round-to-nearest-even
    union { float f; unsigned u; } uu; uu.f = v;
    unsigned x = uu.u;
    unsigned r = (x + 0x7fff + ((x >> 16) & 1)) >> 16;
    int idx = (((c >> 2) << lg) + n) * 4 + (c & 3);
    dst[pa.dstoff[seg] + idx] = (unsigned short)r;
}

// ---------------------------------------------------------------------------
// block-wide sum over 256 threads (4 waves)
__device__ __forceinline__ float blk_sum(float v, float* s_red) {
    for (int off = 32; off > 0; off >>= 1) v += __shfl_down(v, off, 64);
    int tid = threadIdx.x;
    __syncthreads();
    if ((tid & 63) == 0) s_red[tid >> 6] = v;
    __syncthreads();
    return s_red[0] + s_red[1] + s_red[2] + s_red[3];
}

__device__ __forceinline__ float blk_ln(float x, const float* g, const float* bb, float* s_red) {
    int tid = threadIdx.x;
    float mean = blk_sum(x, s_red) * (1.0f / 256.0f);
    float xm = x - mean;
    float var = blk_sum(xm * xm, s_red) * (1.0f / 256.0f);
    return xm / sqrtf(var + 1e-5f) * g[tid] + bb[tid];
}

// ---------------------------------------------------------------------------
// Kernel 1: point-softmax + bilinear gather.
__global__ void gather_kernel(const float* __restrict__ traj, const float* __restrict__ noisy,
                              const float* __restrict__ bev, const float* __restrict__ attn_w,
                              const float* __restrict__ attn_b,
                              float* __restrict__ gw, float* __restrict__ wsumw) {
    int blk = blockIdx.x;
    int b = blk / NM, tid = threadIdx.x;
    __shared__ float s_traj[ND];
    __shared__ float s_ptw[NP];
    __shared__ float s_w[32];
    __shared__ int s_idx[32];

    s_traj[tid] = traj[(size_t)blk * ND + tid];
    __syncthreads();
    if (tid < NP) {
        float acc = attn_b[tid];
        for (int c = 0; c < ND; c++) acc += s_traj[c] * attn_w[c * NP + tid];
        s_ptw[tid] = acc;
    }
    __syncthreads();
    if (tid == 0) {
        float mx = s_ptw[0];
        for (int p = 1; p < NP; p++) mx = fmaxf(mx, s_ptw[p]);
        float e[NP], sum = 0.f;
        for (int p = 0; p < NP; p++) { e[p] = expf(s_ptw[p] - mx); sum += e[p]; }
        for (int p = 0; p < NP; p++) s_ptw[p] = e[p] / sum;
    }
    __syncthreads();
    if (tid < 32) {
        int p = tid >> 2, corner = tid & 3;
        float gx = noisy[((size_t)blk * NP + p) * 2 + 0] * (1.0f / 32.0f);
        float gy = noisy[((size_t)blk * NP + p) * 2 + 1] * (1.0f / 32.0f);
        float x = (gx + 1.0f) * (NW * 0.5f) - 0.5f;
        float y = (gy + 1.0f) * (NH * 0.5f) - 0.5f;
        float x0 = floorf(x), y0 = floorf(y);
        int dx = corner & 1, dy = corner >> 1;
        float wx = dx ? (x - x0) : (x0 + 1.0f - x);
        float wy = dy ? (y - y0) : (y0 + 1.0f - y);
        float xi = x0 + (float)dx, yi = y0 + (float)dy;
        bool valid = (xi >= 0.f) && (xi <= (float)(NW - 1)) && (yi >= 0.f) && (yi <= (float)(NH - 1));
        int xc = (int)fminf(fmaxf(xi, 0.f), (float)(NW - 1));
        int yc = (int)fminf(fmaxf(yi, 0.f), (float)(NH - 1));
        s_w[tid] = wx * wy * (valid ? 1.f : 0.f) * s_ptw[p];
        s_idx[tid] = yc * NW + xc;
    }
    __syncthreads();
    if (tid == 0) {
        float s = 0.f;
        for (int j = 0; j < 32; j++) s += s_w[j];
        wsumw[blk] = s;
    }
    const float* base = bev + (size_t)b * ND * HW + (size_t)tid * HW;
    float acc0 = 0.f, acc1 = 0.f;
    #pragma unroll
    for (int j = 0; j < 32; j += 2) {
        acc0 += s_w[j]     * base[s_idx[j]];
        acc1 += s_w[j + 1] * base[s_idx[j + 1]];
    }
    gw[(size_t)blk * ND + tid] = acc0 + acc1;
}

// ---------------------------------------------------------------------------
// Kernel 2: agents K/V projections, packed bf16 weights, 2 agents per block.
__global__ void kv_kernel(const float* __restrict__ agents,
                          const uint2* __restrict__ wkp, const float* __restrict__ bk,
                          const uint2* __restrict__ wvp, const float* __restrict__ bv,
                          float* __restrict__ K1, float* __restrict__ V1) {
    int blk = blockIdx.x, tid = threadIdx.x;
    int a0 = blk * 2;
    __shared__ __align__(16) float s0[ND], s1[ND];
    s0[tid] = agents[(size_t)a0 * ND + tid];
    s1[tid] = agents[(size_t)(a0 + 1) * ND + tid];
    __syncthreads();
    float k0 = bk[tid], k1 = k0, v0 = bv[tid], v1 = v0;
    const float4* p0 = (const float4*)s0;
    const float4* p1 = (const float4*)s1;
    #pragma unroll 8
    for (int c4 = 0; c4 < 64; ++c4) {
        float4 a0f = p0[c4], a1f = p1[c4];
        uint2 wk = wkp[(c4 << 8) + tid];
        uint2 wv = wvp[(c4 << 8) + tid];
        k0 = fma4(a0f, wk, k0); k1 = fma4(a1f, wk, k1);
        v0 = fma4(a0f, wv, v0); v1 = fma4(a1f, wv, v1);
    }
    K1[(size_t)a0 * ND + tid] = k0;
    K1[(size_t)(a0 + 1) * ND + tid] = k1;
    V1[(size_t)a0 * ND + tid] = v0;
    V1[(size_t)(a0 + 1) * ND + tid] = v1;
}

// ---------------------------------------------------------------------------
// Kernel 3: per-batch precompute (ego collapse + modulation). fp32, tiny.
__global__ void perb_kernel(const float* __restrict__ ego,
                            const float* __restrict__ eq_wv, const float* __restrict__ eq_bv,
                            const float* __restrict__ eq_wo, const float* __restrict__ eq_bo,
                            const float* __restrict__ time_embed,
                            const float* __restrict__ mod_w, const float* __restrict__ mod_b,
                            float* __restrict__ u, float* __restrict__ ss) {
    int b = blockIdx.x, tid = threadIdx.x;
    __shared__ float s_a[ND], s_b[ND];
    s_a[tid] = ego[(size_t)b * ND + tid];
    __syncthreads();
    float v = eq_bv[tid];
    for (int c = 0; c < ND; c++) v += s_a[c] * eq_wv[c * ND + tid];
    s_b[tid] = v;
    __syncthreads();
    float o = eq_bo[tid];
    for (int c = 0; c < ND; c++) o += s_b[c] * eq_wo[c * ND + tid];
    u[(size_t)b * ND + tid] = o;

    float te = time_embed[(size_t)b * ND + tid];
    float sp = log1pf(expf(te));          // softplus
    float me = te * tanhf(sp);            // mish
    __syncthreads();
    s_a[tid] = me;
    __syncthreads();
    for (int jj = 0; jj < 2; jj++) {
        int j = tid + jj * ND;
        float acc = mod_b[j];
        for (int c = 0; c < ND; c++) acc += s_a[c] * mod_w[(size_t)c * 2 * ND + j];
        ss[(size_t)b * 2 * ND + j] = acc;
    }
}

// ---------------------------------------------------------------------------
// Kernel 4: per-token megakernel (packed bf16 weights). one block per (b,m).
struct MegaW {
    const float *traj, *noisy;
    const float *bvb, *bob, *bq, *bo;
    const float *n1g, *n1b, *n2g, *n2b;
    const float *fb1, *fb2, *n3g, *n3b;
    const float *cb1, *cl1g, *cl1b, *cb2, *cl2g, *cl2b, *cw3, *cb3;
    const float *rb1, *rb2, *rw3, *rb3;
};

__global__ void mega_kernel(const float* __restrict__ gw, const float* __restrict__ wsumw,
                            const float* __restrict__ K1, const float* __restrict__ V1,
                            const float* __restrict__ u, const float* __restrict__ ss,
                            const uint2* __restrict__ bvwp, const uint2* __restrict__ bowp,
                            const uint2* __restrict__ wqp, const uint2* __restrict__ wop,
                            const uint2* __restrict__ fw1p, const uint2* __restrict__ fw2p,
                            const uint2* __restrict__ cw1p, const uint2* __restrict__ cw2p,
                            const uint2* __restrict__ rw1p, const uint2* __restrict__ rw2p,
                            MegaW W, float* __restrict__ out) {
    int blk = blockIdx.x;
    int b = blk / NM, tid = threadIdx.x;
    __shared__ __align__(16) float s_a[ND];
    __shared__ __align__(16) float s_b[ND];
    __shared__ __align__(16) float s_h[NFF];
    __shared__ __align__(16) float s_sc[ND];
    __shared__ float s_red[4];

    // --- bev value GEMM: sampled' = gw @ W_v + b_v * wsum
    s_sc[tid] = gw[(size_t)blk * ND + tid];
    float wsw = wsumw[blk];
    __syncthreads();
    float acc = gemm256(bvwp, s_sc, tid, W.bvb[tid] * wsw);
    __syncthreads();
    s_b[tid] = acc;
    __syncthreads();
    // --- bev out GEMM + residual with traj_feature -> t0 in s_a
    acc = gemm256(bowp, s_b, tid, W.bob[tid] + W.traj[(size_t)blk * ND + tid]);
    s_a[tid] = acc;
    __syncthreads();
    // --- agents attention: q projection
    acc = gemm256(wqp, s_a, tid, W.bq[tid]);
    __syncthreads();
    s_b[tid] = acc;   // q
    __syncthreads();
    // scores: thread t -> head h = t>>5, key k = t&31
    int h = tid >> 5, kk = tid & 31;
    {
        const float* Krow = K1 + ((size_t)(b * NA + kk)) * ND + h * 32;
        float sc = 0.f;
        for (int j = 0; j < 32; j++) sc += s_b[h * 32 + j] * Krow[j];
        s_sc[tid] = sc * 0.17677669529663687f;   // 1/sqrt(32)
    }
    __syncthreads();
    // softmax over the 32 keys of this head
    {
        float mx = -1e30f;
        for (int j = 0; j < 32; j++) mx = fmaxf(mx, s_sc[h * 32 + j]);
        float den = 0.f;
        for (int j = 0; j < 32; j++) den += expf(s_sc[h * 32 + j] - mx);
        float p = expf(s_sc[tid] - mx) / den;
        __syncthreads();
        s_sc[tid] = p;
        __syncthreads();
    }
    // attn out: o[d], d = tid, head = tid>>5
    {
        const float* Vb = V1 + (size_t)b * NA * ND;
        float o = 0.f;
        for (int k = 0; k < 32; k++) o += s_sc[h * 32 + k] * Vb[(size_t)k * ND + tid];
        __syncthreads();
        s_b[tid] = o;
        __syncthreads();
    }
    // output proj + residual + LN1
    acc = gemm256(wop, s_b, tid, W.bo[tid] + s_a[tid]);
    float t1 = blk_ln(acc, W.n1g, W.n1b, s_red);
    // ego (collapsed) residual + LN2
    float t2 = blk_ln(t1 + u[(size_t)b * ND + tid], W.n2g, W.n2b, s_red);
    __syncthreads();
    s_a[tid] = t2;
    __syncthreads();
    // --- FFN: h = relu(t2 @ fw1 + fb1)   (K=256, N=1024, 4 outputs/thread)
    {
        float f0 = W.fb1[tid], f1 = W.fb1[tid + 256], f2 = W.fb1[tid + 512], f3 = W.fb1[tid + 768];
        const float4* a4 = (const float4*)s_a;
        #pragma unroll 4
        for (int c4 = 0; c4 < 64; ++c4) {
            float4 a = a4[c4];
            f0 = fma4(a, fw1p[(c4 << 10) + tid], f0);
            f1 = fma4(a, fw1p[(c4 << 10) + 256 + tid], f1);
            f2 = fma4(a, fw1p[(c4 << 10) + 512 + tid], f2);
            f3 = fma4(a, fw1p[(c4 << 10) + 768 + tid], f3);
        }
        s_h[tid] = fmaxf(f0, 0.f);
        s_h[tid + 256] = fmaxf(f1, 0.f);
        s_h[tid + 512] = fmaxf(f2, 0.f);
        s_h[tid + 768] = fmaxf(f3, 0.f);
    }
    __syncthreads();
    // --- FFN2 (K=1024)
    {
        acc = W.fb2[tid];
        const float4* h4 = (const float4*)s_h;
        #pragma unroll 8
        for (int c4 = 0; c4 < 256; ++c4) {
            acc = fma4(h4[c4], fw2p[(c4 << 8) + tid], acc);
        }
    }
    float t3 = blk_ln(acc, W.n3g, W.n3b, s_red);   // no residual, per reference
    // modulation
    float sc1 = ss[(size_t)b * 2 * ND + tid];
    float sh1 = ss[(size_t)b * 2 * ND + ND + tid];
    float tt = t3 * (1.f + sc1) + sh1;
    __syncthreads();
    s_a[tid] = tt;
    __syncthreads();
    // --- cls head
    acc = gemm256(cw1p, s_a, tid, W.cb1[tid]);
    float h1 = blk_ln(fmaxf(acc, 0.f), W.cl1g, W.cl1b, s_red);
    __syncthreads();
    s_b[tid] = h1;
    __syncthreads();
    acc = gemm256(cw2p, s_b, tid, W.cb2[tid]);
    float h2 = blk_ln(fmaxf(acc, 0.f), W.cl2g, W.cl2b, s_red);
    float pc = blk_sum(h2 * W.cw3[tid], s_red);
    if (tid == 0) out[(size_t)NB * NM * NP * 3 + blk] = pc + W.cb3[0];
    // --- reg head
    acc = gemm256(rw1p, s_a, tid, W.rb1[tid]);
    __syncthreads();
    s_b[tid] = fmaxf(acc, 0.f);
    __syncthreads();
    acc = gemm256(rw2p, s_b, tid, W.rb2[tid]);
    __syncthreads();
    s_b[tid] = fmaxf(acc, 0.f);
    __syncthreads();
    if (tid < 24) {
        float r3 = W.rb3[tid];
        for (int c = 0; c < ND; c++) r3 += s_b[c] * W.rw3[c * 24 + tid];
        int ts = tid / 3, k2 = tid % 3;
        float val;
        if (k2 < 2) val = r3 + W.noisy[((size_t)blk * NP + ts) * 2 + k2];
        else        val = tanhf(r3) * 3.14159265358979323846f;
        out[((size_t)blk * NP + ts) * 3 + k2] = val;
    }
}

// ---------------------------------------------------------------------------
extern "C" void kernel_launch(void* const* d_in, const int* in_sizes, int n_in,
                              void* d_out, int out_size, void* d_ws, size_t ws_size,
                              hipStream_t stream) {
    const float* traj   = (const float*)d_in[0];
    const float* noisy  = (const float*)d_in[1];
    const float* bev    = (const float*)d_in[2];
    const float* agents = (const float*)d_in[3];
    const float* ego    = (const float*)d_in[4];
    const float* temb   = (const float*)d_in[5];
    const float* bvw = (const float*)d_in[7];
    const float* bvb = (const float*)d_in[8];
    const float* baw = (const float*)d_in[9];
    const float* bab = (const float*)d_in[10];
    const float* bow = (const float*)d_in[11];
    const float* bob = (const float*)d_in[12];
    const float* aq_wq = (const float*)d_in[13];
    const float* aq_bq = (const float*)d_in[14];
    const float* aq_wk = (const float*)d_in[15];
    const float* aq_bk = (const float*)d_in[16];
    const float* aq_wv = (const float*)d_in[17];
    const float* aq_bv = (const float*)d_in[18];
    const float* aq_wo = (const float*)d_in[19];
    const float* aq_bo = (const float*)d_in[20];
    // 21..24: eq_wq/bq/wk/bk dead (Lk==1 -> softmax==1)
    const float* eq_wv = (const float*)d_in[25];
    const float* eq_bv = (const float*)d_in[26];
    const float* eq_wo = (const float*)d_in[27];
    const float* eq_bo = (const float*)d_in[28];
    const float* fw1 = (const float*)d_in[29];
    const float* fb1 = (const float*)d_in[30];
    const float* fw2 = (const float*)d_in[31];
    const float* fb2 = (const float*)d_in[32];
    const float* n1g = (const float*)d_in[33];
    const float* n1b = (const float*)d_in[34];
    const float* n2g = (const float*)d_in[35];
    const float* n2b = (const float*)d_in[36];
    const float* n3g = (const float*)d_in[37];
    const float* n3b = (const float*)d_in[38];
    const float* modw = (const float*)d_in[39];
    const float* modb = (const float*)d_in[40];
    const float* cw1 = (const float*)d_in[41];
    const float* cb1 = (const float*)d_in[42];
    const float* cl1g = (const float*)d_in[43];
    const float* cl1b = (const float*)d_in[44];
    const float* cw2 = (const float*)d_in[45];
    const float* cb2 = (const float*)d_in[46];
    const float* cl2g = (const float*)d_in[47];
    const float* cl2b = (const float*)d_in[48];
    const float* cw3 = (const float*)d_in[49];
    const float* cb3 = (const float*)d_in[50];
    const float* rw1 = (const float*)d_in[51];
    const float* rb1 = (const float*)d_in[52];
    const float* rw2 = (const float*)d_in[53];
    const float* rb2 = (const float*)d_in[54];
    const float* rw3 = (const float*)d_in[55];
    const float* rb3 = (const float*)d_in[56];

    float* ws = (float*)d_ws;
    float* gw    = ws + WS_GW;
    float* wsumw = ws + WS_WSUM;
    float* K1    = ws + WS_K1;
    float* V1    = ws + WS_V1;
    float* u     = ws + WS_U;
    float* ssb   = ws + WS_SS;
    unsigned short* pk = (unsigned short*)(ws + WS_PACK);

    // ---- pack all GEMM weights to bf16 [K/4][N][4]
    PackArgs pa;
    const float* srcs[12] = {bvw, bow, aq_wq, aq_wo, cw1, cw2, rw1, rw2, aq_wk, aq_wv, fw1, fw2};
    int lg[12]   = {8, 8, 8, 8, 8, 8, 8, 8, 8, 8, 10, 8};
    int el[12]   = {65536, 65536, 65536, 65536, 65536, 65536, 65536, 65536, 65536, 65536, 262144, 262144};
    int off[12]  = {PK_BVW, PK_BOW, PK_WQ, PK_WO, PK_CW1, PK_CW2, PK_RW1, PK_RW2, PK_WK, PK_WV, PK_FW1, PK_FW2};
    for (int i = 0; i < 12; i++) { pa.src[i] = srcs[i]; pa.log2N[i] = lg[i]; pa.elems[i] = el[i]; pa.dstoff[i] = off[i]; }
    pack_kernel<<<dim3(PK_TOTAL / 256), dim3(256), 0, stream>>>(pa, pk);

    gather_kernel<<<dim3(NB * NM), dim3(256), 0, stream>>>(traj, noisy, bev, baw, bab, gw, wsumw);
    kv_kernel<<<dim3(NB * NA / 2), dim3(256), 0, stream>>>(agents,
        (const uint2*)(pk + PK_WK), aq_bk, (const uint2*)(pk + PK_WV), aq_bv, K1, V1);
    perb_kernel<<<dim3(NB), dim3(256), 0, stream>>>(ego, eq_wv, eq_bv, eq_wo, eq_bo, temb, modw, modb, u, ssb);

    MegaW W;
    W.traj = traj; W.noisy = noisy;
    W.bvb = bvb; W.bob = bob; W.bq = aq_bq; W.bo = aq_bo;
    W.n1g = n1g; W.n1b = n1b; W.n2g = n2g; W.n2b = n2b;
    W.fb1 = fb1; W.fb2 = fb2; W.n3g = n3g; W.n3b = n3b;
    W.cb1 = cb1; W.cl1g = cl1g; W.cl1b = cl1b;
    W.cb2 = cb2; W.cl2g = cl2g; W.cl2b = cl2b; W.cw3 = cw3; W.cb3 = cb3;
    W.rb1 = rb1; W.rb2 = rb2; W.rw3 = rw3; W.rb3 = rb3;

    mega_kernel<<<dim3(NB * NM), dim3(256), 0, stream>>>(gw, wsumw, K1, V1, u, ssb,
        (const uint2*)(pk + PK_BVW), (const uint2*)(pk + PK_BOW),
        (const uint2*)(pk + PK_WQ),  (const uint2*)(pk + PK_WO),
        (const uint2*)(pk + PK_FW1), (const uint2*)(pk + PK_FW2),
        (const uint2*)(pk + PK_CW1), (const uint2*)(pk + PK_CW2),
        (const uint2*)(pk + PK_RW1), (const uint2*)(pk + PK_RW2),
        W, (float*)d_out);
}